// Round 13
// baseline (48.996 us; speedup 1.0000x reference)
//
#include <hip/hip_runtime.h>
#include <math.h>

#define DDIM 512
#define BDIM 256
#define NCLS 85742
#define NB1 2048
#define CHUNK1 ((NCLS + NB1 - 1) / NB1)   // 42 rows per block

typedef float f32x4 __attribute__((ext_vector_type(4)));
typedef float f32x2 __attribute__((ext_vector_type(2)));

// ws float layout:
//   [0] Si_acc   [1] Sy_tot   [2] S2_tot
//   [16..143]  aux sy partials (128)
//   [144..271] aux s2 partials (128)
//   [1024 .. 132096)  U: f32x4 [row(256)][quad(128)]   (512 KB)
//   [132096 ...)      partial2: f32x2 [colpair(256)][block(2048)]  (4 MB)
#define WS_UPART 1024
#define WS_PART  (1024 + 256 * 128 * 4)

__device__ __forceinline__ float wave_reduce(float v) {
    #pragma unroll
    for (int off = 32; off > 0; off >>= 1)
        v += __shfl_down(v, off, 64);
    return v;
}

__device__ __forceinline__ float block_reduce(float v, float* smem) {
    const int lane = threadIdx.x & 63;
    const int wid  = threadIdx.x >> 6;
    v = wave_reduce(v);
    if (lane == 0) smem[wid] = v;
    __syncthreads();
    if (wid == 0) {
        v = (lane < (int)(blockDim.x >> 6)) ? smem[lane] : 0.0f;
        v = wave_reduce(v);
    }
    return v;
}

// System-scope (sc0 sc1) 8B load: bypasses L1 and L2, served from L3/HBM.
__device__ __forceinline__ f32x2 ldsys(const unsigned long long* p) {
    unsigned long long v = __hip_atomic_load(p, __ATOMIC_RELAXED,
                                             __HIP_MEMORY_SCOPE_SYSTEM);
    return __builtin_bit_cast(f32x2, v);
}

// K1: colsum partials over a contiguous 42-row chunk. Thread t owns column
// pair (2t, 2t+1); per row one 8B system-scope load. 4-deep rotation.
// partial2 stored transposed [colpair][block]. Aux fold (blocks 0..127)
// computes the colsum-independent terms (Sy, S2, U) with normal loads.
__global__ __launch_bounds__(256, 4)
void colsum_partial(const float* __restrict__ W, const float* __restrict__ mu,
                    const int* __restrict__ label, float* __restrict__ ws,
                    float* __restrict__ out) {
    const int t = threadIdx.x;
    const int b = blockIdx.x;
    if (b == 0 && t == 0) { ws[0] = 0.0f; *out = 0.0f; }

    const unsigned long long* __restrict__ Wu =
        reinterpret_cast<const unsigned long long*>(W);

    const int r0 = b * CHUNK1;
    const int r1 = (r0 + CHUNK1 < NCLS) ? (r0 + CHUNK1) : NCLS;
    const int rows = r1 - r0;

    f32x2 a0 = (f32x2)(0.f), a1 = a0, a2 = a0, a3 = a0;
    const unsigned long long* base = Wu + (size_t)r0 * 256 + t;

    if (rows == CHUNK1) {
        // 42 rows: prologue 4, 9x4 rotation, epilogue 4 + 2
        f32x2 c0 = ldsys(base);
        f32x2 c1 = ldsys(base + 256);
        f32x2 c2 = ldsys(base + 512);
        f32x2 c3 = ldsys(base + 768);
        #pragma unroll
        for (int k = 1; k <= 9; ++k) {
            const unsigned long long* p = base + (size_t)k * 1024;
            a0 += c0;  c0 = ldsys(p);
            a1 += c1;  c1 = ldsys(p + 256);
            a2 += c2;  c2 = ldsys(p + 512);
            a3 += c3;  c3 = ldsys(p + 768);
        }
        a0 += c0; a1 += c1; a2 += c2; a3 += c3;       // rows 36..39
        a0 += ldsys(base + 10240);                     // row 40
        a1 += ldsys(base + 10496);                     // row 41
    } else {
        for (int r = 0; r < rows; ++r)
            a0 += ldsys(base + (size_t)r * 256);
    }
    a0 += a1 + a2 + a3;

    f32x2* partial2 = reinterpret_cast<f32x2*>(ws + WS_PART);
    partial2[(size_t)t * NB1 + b] = a0;   // empty blocks write zeros

    // ---- aux work: blocks 0..127, batch rows 2b, 2b+1 (normal loads) ----
    if (b < 128) {
        const int q = t & 127, rsub = t >> 7;
        const int row = 2 * b + rsub;
        const int lab = label[row];
        const f32x4 m4 = reinterpret_cast<const f32x4*>(mu)[(size_t)row * 128 + q];
        const f32x4 w4 = reinterpret_cast<const f32x4*>(W)[(size_t)lab * 128 + q];
        f32x4 d = w4 - m4;
        f32x4 u = w4 + m4;
        reinterpret_cast<f32x4*>(ws + WS_UPART)[(size_t)row * 128 + q] = u;
        float syp = d.x * d.x + d.y * d.y + d.z * d.z + d.w * d.w;
        float s2p = u.x * u.x + u.y * u.y + u.z * u.z + u.w * u.w;
        __shared__ float rsm[8];
        syp = block_reduce(syp, rsm);
        __syncthreads();
        s2p = block_reduce(s2p, rsm);
        if (t == 0) {
            ws[16 + b]  = syp;
            ws[144 + b] = s2p;
        }
    }
}

// K2: block cp (0..255) finishes colsum for its column pair and adds its
// share of Si's expansion: si_cp = 256*(cs.cs) - 2*(cs.U). Block 0 also
// reduces the aux Sy/S2 partials to scalars.
__global__ __launch_bounds__(256, 4)
void reduce_kernel(float* __restrict__ ws) {
    const int cp = blockIdx.x;      // 0..255 column pair
    const int t = threadIdx.x;
    const f32x2* __restrict__ partial2 =
        reinterpret_cast<const f32x2*>(ws + WS_PART) + (size_t)cp * NB1;
    f32x2 s = (f32x2)(0.f);
    #pragma unroll
    for (int k = 0; k < NB1 / 256; ++k)
        s += partial2[t + k * 256];
    // U for row t, columns (2cp, 2cp+1)
    const f32x4 u4 = reinterpret_cast<const f32x4*>(ws + WS_UPART)[(size_t)t * 128 + (cp >> 1)];
    const f32x2 u2 = (cp & 1) ? u4.zw : u4.xy;

    __shared__ float rsm[8];
    float csx = block_reduce(s.x, rsm);  __syncthreads();
    float csy = block_reduce(s.y, rsm);  __syncthreads();
    float Ux  = block_reduce(u2.x, rsm); __syncthreads();
    float Uy  = block_reduce(u2.y, rsm);
    if (t == 0) {
        float si = 256.0f * (csx * csx + csy * csy) - 2.0f * (csx * Ux + csy * Uy);
        atomicAdd(&ws[0], si);
    }

    if (cp == 0) {
        __syncthreads();
        float syp = (t < 128) ? ws[16 + t]  : 0.0f;
        float s2p = (t < 128) ? ws[144 + t] : 0.0f;
        syp = block_reduce(syp, rsm);
        __syncthreads();
        s2p = block_reduce(s2p, rsm);
        if (t == 0) { ws[1] = syp; ws[2] = s2p; }
    }
}

// K3: loss = sum erf(dy/(sqrt2*std)) + erfc(di/(sqrt2*std)); one f32x4/thread.
__global__ __launch_bounds__(256, 4)
void loss_kernel(const float* __restrict__ stdv, const float* __restrict__ ws,
                 float* __restrict__ out) {
    __shared__ float smem[8];
    const float dy = sqrtf(ws[1]);
    const float di = sqrtf(ws[0] + ws[2]);    // Si = Si_acc + S2
    const float inv_sqrt2 = 0.70710678118654752f;
    const int i = blockIdx.x * 256 + threadIdx.x;     // 32768 f32x4 total
    f32x4 s4 = reinterpret_cast<const f32x4*>(stdv)[i];
    float acc;
    {
        float rx = inv_sqrt2 / s4.x, ry = inv_sqrt2 / s4.y;
        float rz = inv_sqrt2 / s4.z, rw = inv_sqrt2 / s4.w;
        acc  = erff(dy * rx) + erfcf(di * rx);
        acc += erff(dy * ry) + erfcf(di * ry);
        acc += erff(dy * rz) + erfcf(di * rz);
        acc += erff(dy * rw) + erfcf(di * rw);
    }
    acc = block_reduce(acc, smem);
    if (threadIdx.x == 0) atomicAdd(out, acc);
}

extern "C" void kernel_launch(void* const* d_in, const int* in_sizes, int n_in,
                              void* d_out, int out_size, void* d_ws, size_t ws_size,
                              hipStream_t stream) {
    // inputs: 0=x (unused), 1=mu, 2=std, 3=weight, 4=label
    const float* mu    = (const float*)d_in[1];
    const float* stdv  = (const float*)d_in[2];
    const float* W     = (const float*)d_in[3];
    const int*   label = (const int*)d_in[4];
    float* out = (float*)d_out;
    float* ws  = (float*)d_ws;

    colsum_partial<<<NB1, 256, 0, stream>>>(W, mu, label, ws, out);
    reduce_kernel<<<256, 256, 0, stream>>>(ws);
    loss_kernel<<<128, 256, 0, stream>>>(stdv, ws, out);
}